// Round 7
// baseline (465.538 us; speedup 1.0000x reference)
//
#include <hip/hip_runtime.h>
#include <cstdint>
#include <cstddef>

// ExpertMLP fused: out[e] = gelu(x[e] @ wfc[e]) @ wproj[e]
// E=32, CAP=4096, D=256, H=1024. fp32 in/out, bf16 MFMA internally.
// Round 7 — STRUCTURAL PIVOT: producer/consumer wave split.
//   waves 0-3 (P1): h = x@wfc chunk (128h), GELU, -> HC LDS (dbuf)
//   waves 4-7 (P2): acc += hc @ wproj chunk, one phase behind
// Per-wave acc halves -> __launch_bounds__(512,4) -> 2 blocks/CU (16 waves,
// 4/SIMD). Weights DIRECT global->reg (read once; L2-served, XCD-pinned);
// X & HC via LDS (reused). One __syncthreads per phase; no manual vmcnt.

#define NE   32
#define CAPN 4096
#define DDIM 256
#define HDIM 1024

typedef __bf16 bf16x8 __attribute__((ext_vector_type(8)));
typedef __bf16 bf16x4 __attribute__((ext_vector_type(4)));
typedef __bf16 bf16x2 __attribute__((ext_vector_type(2)));
typedef float  f32x4  __attribute__((ext_vector_type(4)));

// LDS (64 KB): XS [64 m][32 slots16B] swz, 32KB | HC 2 x [64 m][16 slots16B] swz
#define B_HC   32768
#define LDSB   65536

// tanh-form GELU via exp2; |err vs erf-GELU| <~3e-3, NaN-free.
__device__ __forceinline__ float gelu_f(float x) {
  float x2 = x * x;
  float u  = x * __builtin_fmaf(0.1029432f, x2, 2.3022078f);
  float t  = __builtin_amdgcn_exp2f(u);
  float r  = __builtin_amdgcn_rcpf(t + 1.0f);
  return __builtin_fmaf(-x, r, x);
}

// ---------------- pre-pass: transpose + cast fp32 -> bf16 -------------------
__global__ __launch_bounds__(256) void tcast_kernel(const float* __restrict__ in,
                                                    __bf16* __restrict__ outp,
                                                    int R, int C) {
  __shared__ __bf16 tl[64][72];
  const int cb = C >> 6;
  const int nb = (R >> 6) * cb;
  const int b  = blockIdx.x;
  const int e  = b / nb;
  const int t  = b - e * nb;
  const int br = t / cb;
  const int bc = t - br * cb;
  const float* src = in + ((size_t)e * R + (size_t)br * 64) * C + (size_t)bc * 64;
#pragma unroll
  for (int i = 0; i < 16; ++i) {
    int idx = i * 256 + threadIdx.x;
    int r = idx >> 6, c = idx & 63;
    tl[c][r] = (__bf16)src[(size_t)r * C + c];
  }
  __syncthreads();
  __bf16* dst = outp + ((size_t)e * C + (size_t)bc * 64) * R + (size_t)br * 64;
#pragma unroll
  for (int i = 0; i < 8; ++i) {
    int idx = i * 512 + threadIdx.x * 2;
    int c = idx >> 6, r = idx & 63;
    bf16x2 p;
    p[0] = tl[c][r];
    p[1] = tl[c][r + 1];
    *(bf16x2*)(dst + (size_t)c * R + r) = p;
  }
}

// ---------------- fused MLP kernel ------------------------------------------
// grid = 2048 (XCD-swizzled: expert e lives on XCD e&7), 512 threads, 64KB LDS.
// BM = 64 m-rows per block; 8 chunks of 128 h; 9 phases.
__global__ __launch_bounds__(512, 4) void fused_mlp(
    const float* __restrict__ x, const __bf16* __restrict__ wfcT,
    const __bf16* __restrict__ wprojT, float* __restrict__ out) {
  extern __shared__ char smem[];
  const int tid  = threadIdx.x;
  const int l15  = tid & 15;
  const int l4   = (tid >> 4) & 3;
  const int w    = tid >> 6;
  const int wq   = w & 3;
  const bool isP2 = (w >= 4);

  // XCD-aware decode: xcd = bid&7 (hw round-robin), 256 slots per XCD cover
  // 4 experts x 64 m-tiles -> each expert's weights live in ONE XCD's L2.
  const int bid  = blockIdx.x;
  const int slot = bid >> 3;
  const int e    = (bid & 7) + 8 * (slot >> 6);
  const int m0   = (slot & 63) << 6;

  const __bf16* wfcT_e   = wfcT   + (size_t)e * HDIM * DDIM;  // [h][d]
  const __bf16* wprojT_e = wprojT + (size_t)e * DDIM * HDIM;  // [d][h]

  // ---- stage X tile [64 m][256 d] fp32 -> bf16 XS (once, all 8 waves) ----
  {
    const float* xb = x + ((size_t)(e * CAPN + m0)) * DDIM;
#pragma unroll
    for (int it = 0; it < 4; ++it) {
      int sid = it * 512 + tid;        // 16B-slot id, 0..2047
      int m   = sid >> 5;
      int s   = sid & 31;
      int phys = (s & 24) | ((s & 7) ^ (m & 7));
      const float4 a0 = *(const float4*)(xb + (size_t)m * DDIM + s * 8);
      const float4 a1 = *(const float4*)(xb + (size_t)m * DDIM + s * 8 + 4);
      bf16x8 v;
      v[0] = (__bf16)a0.x; v[1] = (__bf16)a0.y; v[2] = (__bf16)a0.z; v[3] = (__bf16)a0.w;
      v[4] = (__bf16)a1.x; v[5] = (__bf16)a1.y; v[6] = (__bf16)a1.z; v[7] = (__bf16)a1.w;
      *(bf16x8*)(&smem[m * 512 + phys * 16]) = v;
    }
  }
  __syncthreads();

  f32x4 zero = 0.0f;
  f32x4 acc2[4][4];  // P2: d = wq*64+fd*16, m = fm*16
#pragma unroll
  for (int a = 0; a < 4; ++a)
#pragma unroll
    for (int b = 0; b < 4; ++b) acc2[a][b] = zero;

  for (int p = 0; p < 9; ++p) {
    if (!isP2) {
      if (p < 8) {
        // ---- P1: chunk p. wave (hh,mm): 64h x 32m tile ----
        const int hh = wq >> 1, mm = wq & 1;
        f32x4 acc1[4][2];
#pragma unroll
        for (int a = 0; a < 4; ++a)
#pragma unroll
          for (int b = 0; b < 2; ++b) acc1[a][b] = zero;

        const __bf16* afb = wfcT_e + (size_t)(p * 128 + hh * 64 + l15) * DDIM + l4 * 8;
#pragma unroll 2
        for (int ks = 0; ks < 8; ++ks) {
          bf16x8 bx[2];
#pragma unroll
          for (int fm = 0; fm < 2; ++fm) {
            int m = mm * 32 + fm * 16 + l15;
            int s = ks * 4 + l4;
            int phys = (s & 24) | ((s & 7) ^ (m & 7));
            bx[fm] = *(const bf16x8*)(&smem[m * 512 + phys * 16]);
          }
          __builtin_amdgcn_s_setprio(1);
#pragma unroll
          for (int fh = 0; fh < 4; ++fh) {
            bf16x8 af = *(const bf16x8*)(afb + (size_t)fh * 16 * DDIM + ks * 32);
            acc1[fh][0] = __builtin_amdgcn_mfma_f32_16x16x32_bf16(af, bx[0], acc1[fh][0], 0, 0, 0);
            acc1[fh][1] = __builtin_amdgcn_mfma_f32_16x16x32_bf16(af, bx[1], acc1[fh][1], 0, 0, 0);
          }
          __builtin_amdgcn_s_setprio(0);
        }
        // ---- GELU -> HC[p&1] [64 m][128 h] bf16, swizzled ----
        char* hc = smem + B_HC + (p & 1) * 16384;
#pragma unroll
        for (int fh = 0; fh < 4; ++fh) {
#pragma unroll
          for (int fm = 0; fm < 2; ++fm) {
            int m = mm * 32 + fm * 16 + l15;
            int s = hh * 8 + fh * 2 + (l4 >> 1);
            int phys = (s & 8) | ((s & 7) ^ (m & 7));
            bf16x4 hv;
#pragma unroll
            for (int j = 0; j < 4; ++j) hv[j] = (__bf16)gelu_f(acc1[fh][fm][j]);
            *(bf16x4*)(hc + m * 256 + phys * 16 + (l4 & 1) * 8) = hv;
          }
        }
      }
    } else {
      if (p > 0) {
        // ---- P2: chunk c = p-1. wave dd=wq: 64d x 64m tile ----
        const int c = p - 1;
        const char* hc = smem + B_HC + (c & 1) * 16384;
        const __bf16* afb = wprojT_e + (size_t)(wq * 64 + l15) * HDIM + c * 128 + l4 * 8;
#pragma unroll 2
        for (int ks = 0; ks < 4; ++ks) {
          bf16x8 bx[4];
#pragma unroll
          for (int fm = 0; fm < 4; ++fm) {
            int m = fm * 16 + l15;
            int s = ks * 4 + l4;
            int phys = (s & 8) | ((s & 7) ^ (m & 7));
            bx[fm] = *(const bf16x8*)(hc + m * 256 + phys * 16);
          }
          __builtin_amdgcn_s_setprio(1);
#pragma unroll
          for (int fd = 0; fd < 4; ++fd) {
            bf16x8 af = *(const bf16x8*)(afb + (size_t)fd * 16 * HDIM + ks * 32);
#pragma unroll
            for (int fm = 0; fm < 4; ++fm)
              acc2[fd][fm] = __builtin_amdgcn_mfma_f32_16x16x32_bf16(af, bx[fm], acc2[fd][fm], 0, 0, 0);
          }
          __builtin_amdgcn_s_setprio(0);
        }
      }
    }
    __syncthreads();
  }

  // ---- epilogue (P2 waves only): D rows d = l4*4+j, col m = l15 ----
  if (isP2) {
#pragma unroll
    for (int fd = 0; fd < 4; ++fd) {
#pragma unroll
      for (int fm = 0; fm < 4; ++fm) {
        int m = m0 + fm * 16 + l15;
        int d = wq * 64 + fd * 16 + l4 * 4;
        *(f32x4*)(out + ((size_t)(e * CAPN + m)) * DDIM + d) = acc2[fd][fm];
      }
    }
  }
}

extern "C" void kernel_launch(void* const* d_in, const int* in_sizes, int n_in,
                              void* d_out, int out_size, void* d_ws, size_t ws_size,
                              hipStream_t stream) {
  (void)in_sizes; (void)n_in; (void)out_size; (void)ws_size;
  const float* x     = (const float*)d_in[0];
  const float* wfc   = (const float*)d_in[1];   // [E][D][H]
  const float* wproj = (const float*)d_in[2];   // [E][H][D]
  float* out = (float*)d_out;

  __bf16* wfcT   = (__bf16*)d_ws;
  __bf16* wprojT = (__bf16*)((char*)d_ws + (size_t)NE * DDIM * HDIM * sizeof(__bf16));

  hipFuncSetAttribute((const void*)fused_mlp,
                      hipFuncAttributeMaxDynamicSharedMemorySize, LDSB);

  tcast_kernel<<<dim3(NE * 64), dim3(256), 0, stream>>>(wfc, wfcT, DDIM, HDIM);
  tcast_kernel<<<dim3(NE * 64), dim3(256), 0, stream>>>(wproj, wprojT, HDIM, DDIM);
  fused_mlp<<<dim3(NE * 64), dim3(512), LDSB, stream>>>(x, wfcT, wprojT, out);
}

// Round 8
// 238.865 us; speedup vs baseline: 1.9490x; 1.9490x over previous
//
#include <hip/hip_runtime.h>
#include <cstdint>
#include <cstddef>

// ExpertMLP fused: out[e] = gelu(x[e] @ wfc[e]) @ wproj[e]
// E=32, CAP=4096, D=256, H=1024. fp32 in/out, bf16 MFMA internally.
// Round 8 — BARRIER-FREE inner loops: BM=64, whole H stripe [64m][1024h]
// resident in LDS (128KB). P1 (K=256) runs to completion, GELU, ONE barrier,
// P2 (K=1024) runs to completion. Weights pre-PACKED in d_ws to A-fragment-
// linear 1KB chunks -> each wave A-load is a perfectly coalesced
// global_load_dwordx4 sweep, register-prefetched (dist 1 / dist 2, fully
// unrolled static buffers). 2 barriers per block total.

#define NE   32
#define CAPN 4096
#define DDIM 256
#define HDIM 1024

typedef __bf16 bf16x8 __attribute__((ext_vector_type(8)));
typedef __bf16 bf16x4 __attribute__((ext_vector_type(4)));
typedef float  f32x4  __attribute__((ext_vector_type(4)));

// LDS: XS [64 m][32 slots16B] swz 32KB | H [64 m][128 slots16B] swz 128KB
#define B_H   32768
#define LDSB  163840

// tanh-form GELU via exp2; |err vs erf-GELU| <~3e-3, NaN-free.
__device__ __forceinline__ float gelu_f(float x) {
  float x2 = x * x;
  float u  = x * __builtin_fmaf(0.1029432f, x2, 2.3022078f);
  float t  = __builtin_amdgcn_exp2f(u);
  float r  = __builtin_amdgcn_rcpf(t + 1.0f);
  return __builtin_fmaf(-x, r, x);
}

// ---- pack wfc[e][d][h] -> pw[e][hb(64)][ks(8)] 1KB chunks, A-frag-linear ----
// chunk (hb,ks) pos(r15,sl,j) = wfc[e][ks*32+sl*8+j][hb*16+r15]
__global__ __launch_bounds__(256) void pack_wfc(const float* __restrict__ wfc,
                                                __bf16* __restrict__ pw) {
  __shared__ __bf16 tl[256][18];
  const int b = blockIdx.x, e = b >> 6, hb = b & 63;
  const int t = threadIdx.x;  // t = d
  const float* src = wfc + (size_t)e * DDIM * HDIM + (size_t)t * HDIM + hb * 16;
#pragma unroll
  for (int j = 0; j < 16; ++j) tl[t][j] = (__bf16)src[j];
  __syncthreads();
  const int ks = t >> 5, u0 = t & 31;
  __bf16* dst = pw + (((size_t)e * 64 + hb) * 8 + ks) * 512;
#pragma unroll
  for (int uu = 0; uu < 2; ++uu) {
    int u = u0 + uu * 32;
    int r15 = u >> 2, sl = u & 3;
    bf16x8 v;
#pragma unroll
    for (int j = 0; j < 8; ++j) v[j] = tl[ks * 32 + sl * 8 + j][r15];
    *(bf16x8*)(dst + u * 8) = v;
  }
}

// ---- pack wproj[e][h][d] -> pw[e][db(16)][ks(32)] 1KB chunks --------------
// chunk (db,ks) pos(r15,sl,j) = wproj[e][ks*32+sl*8+j][db*16+r15]
__global__ __launch_bounds__(256) void pack_wpj(const float* __restrict__ wpj,
                                                __bf16* __restrict__ pw) {
  __shared__ __bf16 tl[1024][18];
  const int b = blockIdx.x, e = b >> 4, db = b & 15;
  const int t = threadIdx.x;
  const float* src = wpj + (size_t)e * HDIM * DDIM + db * 16;
#pragma unroll
  for (int i = 0; i < 4; ++i) {
    int h = i * 256 + t;
#pragma unroll
    for (int j = 0; j < 16; ++j) tl[h][j] = (__bf16)src[(size_t)h * DDIM + j];
  }
  __syncthreads();
#pragma unroll
  for (int i = 0; i < 8; ++i) {
    int g = i * 256 + t;
    int ks = g >> 6, u = g & 63;
    int r15 = u >> 2, sl = u & 3;
    bf16x8 v;
#pragma unroll
    for (int j = 0; j < 8; ++j) v[j] = tl[ks * 32 + sl * 8 + j][r15];
    *(bf16x8*)(pw + (((size_t)e * 16 + db) * 32 + ks) * 512 + u * 8) = v;
  }
}

// ---------------- fused MLP kernel ------------------------------------------
// grid 2048 (XCD-pinned: experts 4*xcd..+4 on XCD xcd), 512 thr, 160KB LDS.
// Wave w: P1 owns h-slice w*128..+128 (acc1 8x4), P2 owns d-slice w*32..+32.
__global__ __launch_bounds__(512, 1) void fused_mlp(
    const float* __restrict__ x, const __bf16* __restrict__ pwfc,
    const __bf16* __restrict__ pwpj, float* __restrict__ out) {
  extern __shared__ char smem[];
  const int tid = threadIdx.x;
  const int l15 = tid & 15, l4 = (tid >> 4) & 3, w = tid >> 6;
  const int bid  = blockIdx.x;
  const int slot = bid >> 3;
  const int e    = (bid & 7) * 4 + (slot >> 6);
  const int m0   = (slot & 63) << 6;

  // ---- stage X [64 m][256 d] fp32 -> bf16 XS swizzled ----
  {
    const float* xb = x + ((size_t)(e * CAPN + m0)) * DDIM;
#pragma unroll
    for (int i = 0; i < 4; ++i) {
      int g = i * 512 + tid;
      int m = g >> 5, s = g & 31;
      const float4 a0 = *(const float4*)(xb + (size_t)m * DDIM + s * 8);
      const float4 a1 = *(const float4*)(xb + (size_t)m * DDIM + s * 8 + 4);
      bf16x8 v;
      v[0] = (__bf16)a0.x; v[1] = (__bf16)a0.y; v[2] = (__bf16)a0.z; v[3] = (__bf16)a0.w;
      v[4] = (__bf16)a1.x; v[5] = (__bf16)a1.y; v[6] = (__bf16)a1.z; v[7] = (__bf16)a1.w;
      int phys = (s & 24) | ((s & 7) ^ (m & 7));
      *(bf16x8*)(&smem[m * 512 + phys * 16]) = v;
    }
  }
  __syncthreads();

  f32x4 zero = 0.0f;

  // ================= P1: acc1[128h x 64m], K=256, no barriers =============
  f32x4 acc1[8][4];
#pragma unroll
  for (int a = 0; a < 8; ++a)
#pragma unroll
    for (int b = 0; b < 4; ++b) acc1[a][b] = zero;

  const __bf16* aB1 = pwfc + (size_t)e * (64 * 8 * 512) +
                      (size_t)w * (8 * 8 * 512) + l15 * 32 + l4 * 8;
  bf16x8 wA[2][8];
#define LDW1(B_, KS_) do {                                                     \
    _Pragma("unroll") for (int fh_ = 0; fh_ < 8; ++fh_)                        \
      wA[B_][fh_] = *(const bf16x8*)(aB1 + (fh_ * 8 + (KS_)) * 512);           \
  } while (0)

  LDW1(0, 0);
#pragma unroll
  for (int ks = 0; ks < 8; ++ks) {
    if (ks < 7) {
      if ((ks & 1) == 0) LDW1(1, ks + 1);
      else               LDW1(0, ks + 1);
    }
    bf16x8 bx[4];
#pragma unroll
    for (int fm = 0; fm < 4; ++fm) {
      int m = fm * 16 + l15;
      int s = ks * 4 + l4;
      int phys = (s & 24) | ((s & 7) ^ (m & 7));
      bx[fm] = *(const bf16x8*)(&smem[m * 512 + phys * 16]);
    }
    __builtin_amdgcn_s_setprio(1);
#pragma unroll
    for (int fh = 0; fh < 8; ++fh) {
      const bf16x8 a = (ks & 1) ? wA[1][fh] : wA[0][fh];
#pragma unroll
      for (int fm = 0; fm < 4; ++fm)
        acc1[fh][fm] = __builtin_amdgcn_mfma_f32_16x16x32_bf16(a, bx[fm], acc1[fh][fm], 0, 0, 0);
    }
    __builtin_amdgcn_s_setprio(0);
  }

  // ---- GELU -> H LDS [64 m][1024 h], slot hs = h>>3, phys = hs^(m&7) ----
#pragma unroll
  for (int fh = 0; fh < 8; ++fh) {
    const int hs = w * 16 + fh * 2 + (l4 >> 1);
#pragma unroll
    for (int fm = 0; fm < 4; ++fm) {
      int m = fm * 16 + l15;
      bf16x4 hv;
#pragma unroll
      for (int j = 0; j < 4; ++j) hv[j] = (__bf16)gelu_f(acc1[fh][fm][j]);
      *(bf16x4*)(&smem[B_H + m * 2048 + (hs ^ (m & 7)) * 16 + (l4 & 1) * 8]) = hv;
    }
  }
  __syncthreads();  // the ONLY cross-phase barrier

  // ================= P2: acc2[32d x 64m], K=1024, no barriers =============
  f32x4 acc2[2][4];
#pragma unroll
  for (int a = 0; a < 2; ++a)
#pragma unroll
    for (int b = 0; b < 4; ++b) acc2[a][b] = zero;

  const __bf16* aB2 = pwpj + (size_t)e * (16 * 32 * 512) +
                      (size_t)(w * 2) * (32 * 512) + l15 * 32 + l4 * 8;
  bf16x8 w2[4][2];
#define LDW2(B_, KS_) do {                                                     \
    w2[B_][0] = *(const bf16x8*)(aB2 + (KS_) * 512);                           \
    w2[B_][1] = *(const bf16x8*)(aB2 + (32 + (KS_)) * 512);                    \
  } while (0)

  LDW2(0, 0); LDW2(1, 1);
#pragma unroll
  for (int ks = 0; ks < 32; ++ks) {
    if (ks < 30) LDW2((ks + 2) & 3, ks + 2);
    bf16x8 bx[4];
#pragma unroll
    for (int fm = 0; fm < 4; ++fm) {
      int m = fm * 16 + l15;
      int hs = ks * 4 + l4;
      bx[fm] = *(const bf16x8*)(&smem[B_H + m * 2048 + (hs ^ (m & 7)) * 16]);
    }
    __builtin_amdgcn_s_setprio(1);
#pragma unroll
    for (int fd = 0; fd < 2; ++fd) {
      const bf16x8 a = w2[ks & 3][fd];
#pragma unroll
      for (int fm = 0; fm < 4; ++fm)
        acc2[fd][fm] = __builtin_amdgcn_mfma_f32_16x16x32_bf16(a, bx[fm], acc2[fd][fm], 0, 0, 0);
    }
    __builtin_amdgcn_s_setprio(0);
  }

  // ---- epilogue: D[d][m] -> out[e][m0+m][d] (float4 stores) ----
#pragma unroll
  for (int fd = 0; fd < 2; ++fd) {
#pragma unroll
    for (int fm = 0; fm < 4; ++fm) {
      int m = m0 + fm * 16 + l15;
      int d = w * 32 + fd * 16 + l4 * 4;
      *(f32x4*)(out + ((size_t)(e * CAPN + m)) * DDIM + d) = acc2[fd][fm];
    }
  }
}

extern "C" void kernel_launch(void* const* d_in, const int* in_sizes, int n_in,
                              void* d_out, int out_size, void* d_ws, size_t ws_size,
                              hipStream_t stream) {
  (void)in_sizes; (void)n_in; (void)out_size; (void)ws_size;
  const float* x     = (const float*)d_in[0];
  const float* wfc   = (const float*)d_in[1];   // [E][D][H]
  const float* wproj = (const float*)d_in[2];   // [E][H][D]
  float* out = (float*)d_out;

  // ws: pWfc 16.78MB | pWproj 16.78MB (fragment-linear 1KB chunks)
  __bf16* pwfc = (__bf16*)d_ws;
  __bf16* pwpj = (__bf16*)((char*)d_ws + (size_t)NE * 64 * 8 * 512 * sizeof(__bf16));

  hipFuncSetAttribute((const void*)fused_mlp,
                      hipFuncAttributeMaxDynamicSharedMemorySize, LDSB);

  pack_wfc<<<dim3(NE * 64), dim3(256), 0, stream>>>(wfc, pwfc);
  pack_wpj<<<dim3(NE * 16), dim3(256), 0, stream>>>(wproj, pwpj);
  fused_mlp<<<dim3(2048), dim3(512), LDSB, stream>>>(x, pwfc, pwpj, out);
}